// Round 1
// baseline (204.145 us; speedup 1.0000x reference)
//
#include <hip/hip_runtime.h>

typedef float    f32x4 __attribute__((ext_vector_type(4)));
typedef short    s16x8 __attribute__((ext_vector_type(8)));
typedef _Float16 f16x8 __attribute__((ext_vector_type(8)));
typedef _Float16 f16x4 __attribute__((ext_vector_type(4)));
typedef unsigned short u16x4 __attribute__((ext_vector_type(4)));
typedef unsigned int   u32x4 __attribute__((ext_vector_type(4)));

// B=8, N=1024, F=1024, H=16, D=64
#define NEGBIG (-3.0e38f)

__device__ __forceinline__ unsigned short bf16rne(float f){
  unsigned u = __float_as_uint(f);
  return (unsigned short)((u + 0x7FFFu + ((u >> 16) & 1u)) >> 16);
}
__device__ __forceinline__ float bf16tof(unsigned short b){
  return __uint_as_float(((unsigned)b) << 16);
}

// ---------------- prep: W[h][f][d] -> Wt_hi/Wt_lo[(h*64+d)][f] (bf16 hi/lo) ----
__global__ __launch_bounds__(256) void prepw_kernel(const float* __restrict__ W,
    unsigned short* __restrict__ Wt_hi, unsigned short* __restrict__ Wt_lo)
{
  const int tx = threadIdx.x & 15, ty = threadIdx.x >> 4;
  const int f0 = blockIdx.x * 16, d0 = blockIdx.y * 16, hh = blockIdx.z;
  __shared__ float t[16][17];
  t[ty][tx] = W[(size_t)hh * 65536 + (size_t)(f0 + ty) * 64 + (d0 + tx)];
  __syncthreads();
  float v = t[tx][ty];  // = W[hh][f0+tx][d0+ty]
  unsigned short hi = bf16rne(v);
  unsigned short lo = bf16rne(v - bf16tof(hi));
  size_t o = (size_t)(hh * 64 + d0 + ty) * 1024 + (f0 + tx);
  Wt_hi[o] = hi;
  Wt_lo[o] = lo;
}

// ---------------- prep: adj (int32) -> bitmask words --------------------------
__global__ __launch_bounds__(256) void adjmask_kernel(const int* __restrict__ adj,
    unsigned* __restrict__ maskb)
{
  const int lane = threadIdx.x & 63;
  int gw = (blockIdx.x * 256 + threadIdx.x) >> 6;  // wave id, 4096 total
  for (int s = gw; s < 131072; s += 4096) {
    int a = adj[(size_t)s * 64 + lane];
    unsigned long long m = __ballot(a > 0);
    if (lane == 0) {
      maskb[s * 2]     = (unsigned)m;
      maskb[s * 2 + 1] = (unsigned)(m >> 32);
    }
  }
}

// ---------------- Wh = x @ Wt^T, 3-term bf16 split, fp32 accum ----------------
// A = x [8192 x 1024] f32 (split hi/lo on the fly); B^T = Wt [1024(hd) x 1024(f)]
// out: Wh f32 [8192][1024], WhT f16 [b][h][d][n] for the PV kernel.
__global__ __launch_bounds__(256, 2) void gemm_kernel(const float* __restrict__ x,
    const unsigned short* __restrict__ Btg_hi, const unsigned short* __restrict__ Btg_lo,
    float* __restrict__ Wh, _Float16* __restrict__ WhT)
{
  __shared__ unsigned short Ah[128 * 40], Al[128 * 40], Bh[128 * 40], Bl[128 * 40];
  const int tid  = threadIdx.x;
  const int lane = tid & 63, wave = tid >> 6;
  const int m0 = blockIdx.x * 128, n0 = blockIdx.y * 128;
  const int wm = (wave & 1) * 64, wn = (wave >> 1) * 64;
  const int rA = lane & 15, kg = lane >> 4;

  f32x4 acc[4][4] = {};

  for (int k0 = 0; k0 < 1024; k0 += 32) {
    // stage A: 128 rows x 32 f32 -> hi/lo bf16 (padded stride 40)
#pragma unroll
    for (int r = 0; r < 4; ++r) {
      int flat = r * 256 + tid;          // float4 units, 8 per row
      int row = flat >> 3;
      int c4  = (flat & 7) << 2;
      f32x4 v = *reinterpret_cast<const f32x4*>(&x[(size_t)(m0 + row) * 1024 + k0 + c4]);
      u16x4 hi, lo;
#pragma unroll
      for (int e = 0; e < 4; ++e) {
        unsigned short h = bf16rne(v[e]);
        hi[e] = h;
        lo[e] = bf16rne(v[e] - bf16tof(h));
      }
      *reinterpret_cast<u16x4*>(&Ah[row * 40 + c4]) = hi;
      *reinterpret_cast<u16x4*>(&Al[row * 40 + c4]) = lo;
    }
    // stage B: 128 rows(hd) x 32 k bf16 (hi & lo), 16B chunks
#pragma unroll
    for (int r = 0; r < 2; ++r) {
      int flat = r * 256 + tid;          // 16B units, 4 per row
      int row = flat >> 2;
      int o8  = (flat & 3) << 3;
      size_t g = (size_t)(n0 + row) * 1024 + k0 + o8;
      *reinterpret_cast<u32x4*>(&Bh[row * 40 + o8]) = *reinterpret_cast<const u32x4*>(&Btg_hi[g]);
      *reinterpret_cast<u32x4*>(&Bl[row * 40 + o8]) = *reinterpret_cast<const u32x4*>(&Btg_lo[g]);
    }
    __syncthreads();

    s16x8 ah[4], al[4], bh[4], bl[4];
#pragma unroll
    for (int i = 0; i < 4; ++i) {
      int ro = (wm + i * 16 + rA) * 40 + kg * 8;
      ah[i] = *reinterpret_cast<const s16x8*>(&Ah[ro]);
      al[i] = *reinterpret_cast<const s16x8*>(&Al[ro]);
    }
#pragma unroll
    for (int j = 0; j < 4; ++j) {
      int ro = (wn + j * 16 + rA) * 40 + kg * 8;
      bh[j] = *reinterpret_cast<const s16x8*>(&Bh[ro]);
      bl[j] = *reinterpret_cast<const s16x8*>(&Bl[ro]);
    }
#pragma unroll
    for (int i = 0; i < 4; ++i) {
#pragma unroll
      for (int j = 0; j < 4; ++j) {
        acc[i][j] = __builtin_amdgcn_mfma_f32_16x16x32_bf16(ah[i], bh[j], acc[i][j], 0, 0, 0);
        acc[i][j] = __builtin_amdgcn_mfma_f32_16x16x32_bf16(ah[i], bl[j], acc[i][j], 0, 0, 0);
        acc[i][j] = __builtin_amdgcn_mfma_f32_16x16x32_bf16(al[i], bh[j], acc[i][j], 0, 0, 0);
      }
    }
    __syncthreads();
  }

  // epilogue: Wh f32 [m][n] and WhT f16 [(bh*64+d)*1024 + n-within-batch]
#pragma unroll
  for (int i = 0; i < 4; ++i) {
    int gm0 = m0 + wm + i * 16 + kg * 4;  // 4 consecutive rows
#pragma unroll
    for (int j = 0; j < 4; ++j) {
      int gn = n0 + wn + j * 16 + rA;
#pragma unroll
      for (int jj = 0; jj < 4; ++jj)
        Wh[(size_t)(gm0 + jj) * 1024 + gn] = acc[i][j][jj];
      int bb = gm0 >> 10, nn = gm0 & 1023;
      int hh = gn >> 6,  dd = gn & 63;
      f16x4 hv;
#pragma unroll
      for (int jj = 0; jj < 4; ++jj) hv[jj] = (_Float16)acc[i][j][jj];
      *reinterpret_cast<f16x4*>(&WhT[((size_t)((bb * 16 + hh) * 64 + dd) << 10) + nn]) = hv;
    }
  }
}

// ---------------- f1/f2: per-row dot of Wh with a1/a2 -------------------------
__global__ __launch_bounds__(256, 4) void f1f2_kernel(const float* __restrict__ Wh,
    const float* __restrict__ a1, const float* __restrict__ a2,
    float* __restrict__ f1, float* __restrict__ f2)
{
  const int tid = threadIdx.x, lane = tid & 63, wave = tid >> 6;
  const int row = blockIdx.x * 4 + wave;   // 0..8191  (= b*1024+n)
  const int b = row >> 10, n = row & 1023;
#pragma unroll
  for (int it = 0; it < 16; ++it) {        // it == head h
    float wv = Wh[(size_t)row * 1024 + it * 64 + lane];
    float p1 = wv * a1[it * 64 + lane];
    float p2 = wv * a2[it * 64 + lane];
#pragma unroll
    for (int off = 32; off; off >>= 1) {
      p1 += __shfl_xor(p1, off);
      p2 += __shfl_xor(p2, off);
    }
    if (lane == 0) {
      f1[(size_t)(b * 16 + it) * 1024 + n] = p1;
      f2[(size_t)(b * 16 + it) * 1024 + n] = p2;
    }
  }
}

// ---------------- per-row masked max + softmax denominator --------------------
__global__ __launch_bounds__(256, 4) void maxdenom_kernel(const float* __restrict__ f1,
    const float* __restrict__ f2, const unsigned* __restrict__ maskb,
    float* __restrict__ Mx, float* __restrict__ rden)
{
  const int tid = threadIdx.x, lane = tid & 63, wave = tid >> 6;
  const int gid = blockIdx.x * 4 + wave;   // bh*1024 + n ; 4 rows share bh
  const int bh = gid >> 10, n = gid & 1023, b = bh >> 4;
  __shared__ float f2s[1024];
  *reinterpret_cast<f32x4*>(&f2s[tid * 4]) =
      *reinterpret_cast<const f32x4*>(&f2[(size_t)bh * 1024 + tid * 4]);
  __syncthreads();
  const unsigned* mr = maskb + ((size_t)(b << 10) + n) * 32;
  const float f1v = f1[gid];
  float sc[16];
  float mx = NEGBIG;
#pragma unroll
  for (int it = 0; it < 16; ++it) {
    float v = f2s[it * 64 + lane];
    unsigned w = mr[it * 2 + (lane >> 5)];
    float s = f1v + v;
    float e = fmaxf(s, 0.2f * s);
    sc[it] = ((w >> (lane & 31)) & 1u) ? e : NEGBIG;
    mx = fmaxf(mx, sc[it]);
  }
#pragma unroll
  for (int off = 32; off; off >>= 1) mx = fmaxf(mx, __shfl_xor(mx, off));
  float sum = 0.f;
#pragma unroll
  for (int it = 0; it < 16; ++it) sum += __expf(sc[it] - mx);
#pragma unroll
  for (int off = 32; off; off >>= 1) sum += __shfl_xor(sum, off);
  if (lane == 0) {
    Mx[gid] = mx;
    rden[gid] = sum > 0.f ? 1.0f / sum : 0.f;
  }
}

// ---------------- PV: y[b][n][h*64+d] = (sum_m p * Wh[m][d]) / denom ----------
__global__ __launch_bounds__(256, 2) void pv_kernel(const _Float16* __restrict__ WhT,
    const float* __restrict__ f1, const float* __restrict__ f2,
    const float* __restrict__ Mx, const float* __restrict__ rden,
    const unsigned* __restrict__ maskb, float* __restrict__ y)
{
  const int tid = threadIdx.x, lane = tid & 63, wave = tid >> 6;
  const int rb = blockIdx.x, h = blockIdx.y, b = blockIdx.z;
  const int bh = b * 16 + h;
  const int n0 = rb * 128;
  const _Float16* whtb = WhT + ((size_t)bh << 16);  // 64*1024 per (b,h)

  __shared__ _Float16 Bs[64 * 72];
  __shared__ float f2s[1024];
  __shared__ float f1s[128], Mls[128], rds[128];
  __shared__ unsigned msk[128 * 33];

  *reinterpret_cast<f32x4*>(&f2s[tid * 4]) =
      *reinterpret_cast<const f32x4*>(&f2[(size_t)bh * 1024 + tid * 4]);
  if (tid < 128) {
    int g = bh * 1024 + n0 + tid;
    f1s[tid] = f1[g];
    Mls[tid] = Mx[g];
    rds[tid] = rden[g];
  }
#pragma unroll
  for (int r = 0; r < 16; ++r) {
    int flat = r * 256 + tid;  // 0..4095
    int row = flat >> 5, w = flat & 31;
    msk[row * 33 + w] = maskb[((size_t)(b << 10) + n0 + row) * 32 + w];
  }
  __syncthreads();

  const int rA = lane & 15, kg = lane >> 4;
  const int wrow = wave * 32;
  f32x4 acc[2][4] = {};
  int   rloc[2];
  float f1v[2], Mv[2];
#pragma unroll
  for (int t = 0; t < 2; ++t) {
    rloc[t] = wrow + t * 16 + rA;
    f1v[t] = f1s[rloc[t]];
    Mv[t]  = Mls[rloc[t]];
  }

  for (int m0 = 0; m0 < 1024; m0 += 64) {
    // stage Bs = WhT[d][m0..m0+64) f16, padded stride 72
#pragma unroll
    for (int r = 0; r < 2; ++r) {
      int flat = r * 256 + tid;
      int d = flat >> 3, o = (flat & 7) << 3;
      *reinterpret_cast<u32x4*>(&Bs[d * 72 + o]) =
          *reinterpret_cast<const u32x4*>(&whtb[(size_t)d * 1024 + m0 + o]);
    }
    __syncthreads();
#pragma unroll
    for (int ks = 0; ks < 2; ++ks) {
      int kbase = m0 + ks * 32 + kg * 8;
      f32x4 fa = *reinterpret_cast<const f32x4*>(&f2s[kbase]);
      f32x4 fb = *reinterpret_cast<const f32x4*>(&f2s[kbase + 4]);
      f16x8 pa[2];
#pragma unroll
      for (int t = 0; t < 2; ++t) {
        unsigned mw = msk[rloc[t] * 33 + (m0 >> 5) + ks];
#pragma unroll
        for (int jj = 0; jj < 8; ++jj) {
          float f2j = (jj < 4) ? fa[jj] : fb[jj - 4];
          float s = f1v[t] + f2j;
          float e = fmaxf(s, 0.2f * s);
          float p = ((mw >> (kg * 8 + jj)) & 1u) ? __expf(e - Mv[t]) : 0.0f;
          pa[t][jj] = (_Float16)p;
        }
      }
#pragma unroll
      for (int j = 0; j < 4; ++j) {
        f16x8 bf = *reinterpret_cast<const f16x8*>(&Bs[(j * 16 + rA) * 72 + ks * 32 + kg * 8]);
        acc[0][j] = __builtin_amdgcn_mfma_f32_16x16x32_f16(pa[0], bf, acc[0][j], 0, 0, 0);
        acc[1][j] = __builtin_amdgcn_mfma_f32_16x16x32_f16(pa[1], bf, acc[1][j], 0, 0, 0);
      }
    }
    __syncthreads();
  }

#pragma unroll
  for (int t = 0; t < 2; ++t) {
#pragma unroll
    for (int j = 0; j < 4; ++j) {
#pragma unroll
      for (int jj = 0; jj < 4; ++jj) {
        int row = wrow + t * 16 + kg * 4 + jj;
        int n = n0 + row, d = j * 16 + rA;
        y[(((size_t)b * 1024 + n) << 10) + h * 64 + d] = acc[t][j][jj] * rds[row];
      }
    }
  }
}

extern "C" void kernel_launch(void* const* d_in, const int* in_sizes, int n_in,
                              void* d_out, int out_size, void* d_ws, size_t ws_size,
                              hipStream_t stream)
{
  const float* x  = (const float*)d_in[0];
  const int*   adj = (const int*)d_in[1];
  const float* W  = (const float*)d_in[2];
  const float* a1 = (const float*)d_in[3];
  const float* a2 = (const float*)d_in[4];
  float* y = (float*)d_out;

  char* ws = (char*)d_ws;
  unsigned short* Wt_hi = (unsigned short*)(ws);
  unsigned short* Wt_lo = (unsigned short*)(ws + ((size_t)2 << 20));
  unsigned*       maskb = (unsigned*)(ws + ((size_t)4 << 20));
  float* f1   = (float*)(ws + ((size_t)5 << 20));
  float* f2   = (float*)(ws + ((size_t)5 << 20) + ((size_t)512 << 10));
  float* Mx   = (float*)(ws + ((size_t)6 << 20));
  float* rden = (float*)(ws + ((size_t)6 << 20) + ((size_t)512 << 10));
  float* Wh   = (float*)(ws + ((size_t)7 << 20));
  _Float16* WhT = (_Float16*)(ws + ((size_t)39 << 20));

  prepw_kernel<<<dim3(64, 4, 16), 256, 0, stream>>>(W, Wt_hi, Wt_lo);
  adjmask_kernel<<<1024, 256, 0, stream>>>(adj, maskb);
  gemm_kernel<<<dim3(64, 8), 256, 0, stream>>>(x, Wt_hi, Wt_lo, Wh, WhT);
  f1f2_kernel<<<2048, 256, 0, stream>>>(Wh, a1, a2, f1, f2);
  maxdenom_kernel<<<32768, 256, 0, stream>>>(f1, f2, maskb, Mx, rden);
  pv_kernel<<<dim3(8, 16, 8), 256, 0, stream>>>(WhT, f1, f2, Mx, rden, maskb, y);
}

// Round 3
// 160.199 us; speedup vs baseline: 1.2743x; 1.2743x over previous
//
#include <hip/hip_runtime.h>

typedef float    f32x4 __attribute__((ext_vector_type(4)));
typedef short    s16x8 __attribute__((ext_vector_type(8)));
typedef _Float16 f16x8 __attribute__((ext_vector_type(8)));
typedef _Float16 f16x4 __attribute__((ext_vector_type(4)));
typedef unsigned int   u32x4 __attribute__((ext_vector_type(4)));

// B=8, N=1024, F=1024, H=16, D=64
#define NEGBIG (-3.0e38f)

__device__ __forceinline__ unsigned short bf16rne(float f){
  unsigned u = __float_as_uint(f);
  return (unsigned short)((u + 0x7FFFu + ((u >> 16) & 1u)) >> 16);
}

// ---------------- prep: W[h][f][d] -> Wt[(h*64+d)][f] (bf16) ------------------
__global__ __launch_bounds__(256) void prepw_kernel(const float* __restrict__ W,
    unsigned short* __restrict__ Wt)
{
  const int tx = threadIdx.x & 15, ty = threadIdx.x >> 4;
  const int f0 = blockIdx.x * 16, d0 = blockIdx.y * 16, hh = blockIdx.z;
  __shared__ float t[16][17];
  t[ty][tx] = W[(size_t)hh * 65536 + (size_t)(f0 + ty) * 64 + (d0 + tx)];
  __syncthreads();
  float v = t[tx][ty];  // = W[hh][f0+tx][d0+ty]
  size_t o = (size_t)(hh * 64 + d0 + ty) * 1024 + (f0 + tx);
  Wt[o] = bf16rne(v);
}

// ---------------- prep: adj (int32) -> bitmask words --------------------------
__global__ __launch_bounds__(256) void adjmask_kernel(const int* __restrict__ adj,
    unsigned* __restrict__ maskb)
{
  const int lane = threadIdx.x & 63;
  int gw = (blockIdx.x * 256 + threadIdx.x) >> 6;  // wave id, 4096 total
  for (int s = gw; s < 131072; s += 4096) {
    int a = adj[(size_t)s * 64 + lane];
    unsigned long long m = __ballot(a > 0);
    if (lane == 0) {
      maskb[s * 2]     = (unsigned)m;
      maskb[s * 2 + 1] = (unsigned)(m >> 32);
    }
  }
}

// ---------------- Wh = x @ Wt^T (bf16 MFMA, fp32 accum) -----------------------
// A = x [8192 x 1024] f32 (bf16 convert on the fly); B^T = Wt [1024(hd) x 1024(f)]
// out: WhT f16 [b][h][d][n] for the PV kernel, plus fused f1/f2 epilogue.
__global__ __launch_bounds__(256, 3) void gemm_kernel(const float* __restrict__ x,
    const unsigned short* __restrict__ Btg,
    const float* __restrict__ a1, const float* __restrict__ a2,
    _Float16* __restrict__ WhT, float* __restrict__ f1, float* __restrict__ f2)
{
  __shared__ unsigned short Ah[128 * 40], Bh[128 * 40];
  const int tid  = threadIdx.x;
  const int lane = tid & 63, wave = tid >> 6;
  const int m0 = blockIdx.x * 128, n0 = blockIdx.y * 128;
  const int wm = (wave & 1) * 64, wn = (wave >> 1) * 64;
  const int rA = lane & 15, kg = lane >> 4;

  f32x4 acc[4][4] = {};

  for (int k0 = 0; k0 < 1024; k0 += 32) {
    // stage A: 128 rows x 32 f32 -> bf16 (padded stride 40)
#pragma unroll
    for (int r = 0; r < 4; ++r) {
      int flat = r * 256 + tid;          // float4 units, 8 per row
      int row = flat >> 3;
      int c4  = (flat & 7) << 2;
      f32x4 v = *reinterpret_cast<const f32x4*>(&x[(size_t)(m0 + row) * 1024 + k0 + c4]);
      uint2 pk;
      pk.x = (unsigned)bf16rne(v[0]) | ((unsigned)bf16rne(v[1]) << 16);
      pk.y = (unsigned)bf16rne(v[2]) | ((unsigned)bf16rne(v[3]) << 16);
      *reinterpret_cast<uint2*>(&Ah[row * 40 + c4]) = pk;
    }
    // stage B: 128 rows(hd) x 32 k bf16, 16B chunks
#pragma unroll
    for (int r = 0; r < 2; ++r) {
      int flat = r * 256 + tid;          // 16B units, 4 per row
      int row = flat >> 2;
      int o8  = (flat & 3) << 3;
      size_t g = (size_t)(n0 + row) * 1024 + k0 + o8;
      *reinterpret_cast<u32x4*>(&Bh[row * 40 + o8]) = *reinterpret_cast<const u32x4*>(&Btg[g]);
    }
    __syncthreads();

    s16x8 ah[4], bh[4];
#pragma unroll
    for (int i = 0; i < 4; ++i)
      ah[i] = *reinterpret_cast<const s16x8*>(&Ah[(wm + i * 16 + rA) * 40 + kg * 8]);
#pragma unroll
    for (int j = 0; j < 4; ++j)
      bh[j] = *reinterpret_cast<const s16x8*>(&Bh[(wn + j * 16 + rA) * 40 + kg * 8]);
#pragma unroll
    for (int i = 0; i < 4; ++i)
#pragma unroll
      for (int j = 0; j < 4; ++j)
        acc[i][j] = __builtin_amdgcn_mfma_f32_16x16x32_bf16(ah[i], bh[j], acc[i][j], 0, 0, 0);
    __syncthreads();
  }

  // epilogue 1: WhT f16 [(bh*64+d)*1024 + n-within-batch]
#pragma unroll
  for (int i = 0; i < 4; ++i) {
    int gm0 = m0 + wm + i * 16 + kg * 4;  // 4 consecutive rows
#pragma unroll
    for (int j = 0; j < 4; ++j) {
      int gn = n0 + wn + j * 16 + rA;
      int bb = gm0 >> 10, nn = gm0 & 1023;
      int hh = gn >> 6,  dd = gn & 63;
      f16x4 hv;
#pragma unroll
      for (int jj = 0; jj < 4; ++jj) hv[jj] = (_Float16)acc[i][j][jj];
      *reinterpret_cast<f16x4*>(&WhT[((size_t)((bb * 16 + hh) * 64 + dd) << 10) + nn]) = hv;
    }
  }

  // epilogue 2: fused f1/f2 (this wave's 64 cols = one complete head)
  const int hw = (n0 + wn) >> 6;        // absolute head 0..15
  float a1v[4], a2v[4];
#pragma unroll
  for (int j = 0; j < 4; ++j) {
    int d = j * 16 + rA;
    a1v[j] = a1[hw * 64 + d];
    a2v[j] = a2[hw * 64 + d];
  }
#pragma unroll
  for (int i = 0; i < 4; ++i) {
#pragma unroll
    for (int jj = 0; jj < 4; ++jj) {
      float s1 = 0.f, s2 = 0.f;
#pragma unroll
      for (int j = 0; j < 4; ++j) {
        float v = acc[i][j][jj];
        s1 += v * a1v[j];
        s2 += v * a2v[j];
      }
#pragma unroll
      for (int off = 1; off < 16; off <<= 1) {
        s1 += __shfl_xor(s1, off);
        s2 += __shfl_xor(s2, off);
      }
      if (rA == 0) {
        int gm = m0 + wm + i * 16 + kg * 4 + jj;
        int bb = gm >> 10, nn = gm & 1023;
        size_t o = (size_t)(bb * 16 + hw) * 1024 + nn;
        f1[o] = s1;
        f2[o] = s2;
      }
    }
  }
}

// ---------------- per-row masked max + softmax denominator --------------------
__global__ __launch_bounds__(256, 4) void maxdenom_kernel(const float* __restrict__ f1,
    const float* __restrict__ f2, const unsigned* __restrict__ maskb,
    float* __restrict__ Mx, float* __restrict__ rden)
{
  const int tid = threadIdx.x, lane = tid & 63, wave = tid >> 6;
  const int gid = blockIdx.x * 4 + wave;   // bh*1024 + n ; 4 rows share bh
  const int bh = gid >> 10, n = gid & 1023, b = bh >> 4;
  __shared__ float f2s[1024];
  *reinterpret_cast<f32x4*>(&f2s[tid * 4]) =
      *reinterpret_cast<const f32x4*>(&f2[(size_t)bh * 1024 + tid * 4]);
  __syncthreads();
  const unsigned* mr = maskb + ((size_t)(b << 10) + n) * 32;
  const float f1v = f1[gid];
  float sc[16];
  float mx = NEGBIG;
#pragma unroll
  for (int it = 0; it < 16; ++it) {
    float v = f2s[it * 64 + lane];
    unsigned w = mr[it * 2 + (lane >> 5)];
    float s = f1v + v;
    float e = fmaxf(s, 0.2f * s);
    sc[it] = ((w >> (lane & 31)) & 1u) ? e : NEGBIG;
    mx = fmaxf(mx, sc[it]);
  }
#pragma unroll
  for (int off = 32; off; off >>= 1) mx = fmaxf(mx, __shfl_xor(mx, off));
  float sum = 0.f;
#pragma unroll
  for (int it = 0; it < 16; ++it) sum += __expf(sc[it] - mx);
#pragma unroll
  for (int off = 32; off; off >>= 1) sum += __shfl_xor(sum, off);
  if (lane == 0) {
    Mx[gid] = mx;
    rden[gid] = sum > 0.f ? 1.0f / sum : 0.f;
  }
}

// ---------------- PV: y[b][n][h*64+d] = (sum_m p * Wh[m][d]) / denom ----------
__global__ __launch_bounds__(256, 2) void pv_kernel(const _Float16* __restrict__ WhT,
    const float* __restrict__ f1, const float* __restrict__ f2,
    const float* __restrict__ Mx, const float* __restrict__ rden,
    const unsigned* __restrict__ maskb, float* __restrict__ y)
{
  const int tid = threadIdx.x, lane = tid & 63, wave = tid >> 6;
  const int rb = blockIdx.x, h = blockIdx.y, b = blockIdx.z;
  const int bh = b * 16 + h;
  const int n0 = rb * 128;
  const _Float16* whtb = WhT + ((size_t)bh << 16);  // 64*1024 per (b,h)

  __shared__ _Float16 Bs[64 * 72];
  __shared__ float f2s[1024];
  __shared__ float f1s[128], Mls[128], rds[128];
  __shared__ unsigned msk[128 * 33];

  *reinterpret_cast<f32x4*>(&f2s[tid * 4]) =
      *reinterpret_cast<const f32x4*>(&f2[(size_t)bh * 1024 + tid * 4]);
  if (tid < 128) {
    int g = bh * 1024 + n0 + tid;
    f1s[tid] = f1[g];
    Mls[tid] = Mx[g];
    rds[tid] = rden[g];
  }
#pragma unroll
  for (int r = 0; r < 16; ++r) {
    int flat = r * 256 + tid;  // 0..4095
    int row = flat >> 5, w = flat & 31;
    msk[row * 33 + w] = maskb[((size_t)(b << 10) + n0 + row) * 32 + w];
  }
  __syncthreads();

  const int rA = lane & 15, kg = lane >> 4;
  const int wrow = wave * 32;
  f32x4 acc[2][4] = {};
  int   rloc[2];
  float f1v[2], Mv[2];
#pragma unroll
  for (int t = 0; t < 2; ++t) {
    rloc[t] = wrow + t * 16 + rA;
    f1v[t] = f1s[rloc[t]];
    Mv[t]  = Mls[rloc[t]];
  }

  for (int m0 = 0; m0 < 1024; m0 += 64) {
    // stage Bs = WhT[d][m0..m0+64) f16, padded stride 72
#pragma unroll
    for (int r = 0; r < 2; ++r) {
      int flat = r * 256 + tid;
      int d = flat >> 3, o = (flat & 7) << 3;
      *reinterpret_cast<u32x4*>(&Bs[d * 72 + o]) =
          *reinterpret_cast<const u32x4*>(&whtb[(size_t)d * 1024 + m0 + o]);
    }
    __syncthreads();
#pragma unroll
    for (int ks = 0; ks < 2; ++ks) {
      int kbase = m0 + ks * 32 + kg * 8;
      f32x4 fa = *reinterpret_cast<const f32x4*>(&f2s[kbase]);
      f32x4 fb = *reinterpret_cast<const f32x4*>(&f2s[kbase + 4]);
      f16x8 pa[2];
#pragma unroll
      for (int t = 0; t < 2; ++t) {
        unsigned mw = msk[rloc[t] * 33 + (m0 >> 5) + ks];
#pragma unroll
        for (int jj = 0; jj < 8; ++jj) {
          float f2j = (jj < 4) ? fa[jj] : fb[jj - 4];
          float s = f1v[t] + f2j;
          float e = fmaxf(s, 0.2f * s);
          float p = ((mw >> (kg * 8 + jj)) & 1u) ? __expf(e - Mv[t]) : 0.0f;
          pa[t][jj] = (_Float16)p;
        }
      }
#pragma unroll
      for (int j = 0; j < 4; ++j) {
        f16x8 bf = *reinterpret_cast<const f16x8*>(&Bs[(j * 16 + rA) * 72 + ks * 32 + kg * 8]);
        acc[0][j] = __builtin_amdgcn_mfma_f32_16x16x32_f16(pa[0], bf, acc[0][j], 0, 0, 0);
        acc[1][j] = __builtin_amdgcn_mfma_f32_16x16x32_f16(pa[1], bf, acc[1][j], 0, 0, 0);
      }
    }
    __syncthreads();
  }

#pragma unroll
  for (int t = 0; t < 2; ++t) {
#pragma unroll
    for (int j = 0; j < 4; ++j) {
#pragma unroll
      for (int jj = 0; jj < 4; ++jj) {
        int row = wrow + t * 16 + kg * 4 + jj;
        int n = n0 + row, d = j * 16 + rA;
        y[(((size_t)b * 1024 + n) << 10) + h * 64 + d] = acc[t][j][jj] * rds[row];
      }
    }
  }
}

extern "C" void kernel_launch(void* const* d_in, const int* in_sizes, int n_in,
                              void* d_out, int out_size, void* d_ws, size_t ws_size,
                              hipStream_t stream)
{
  const float* x  = (const float*)d_in[0];
  const int*   adj = (const int*)d_in[1];
  const float* W  = (const float*)d_in[2];
  const float* a1 = (const float*)d_in[3];
  const float* a2 = (const float*)d_in[4];
  float* y = (float*)d_out;

  char* ws = (char*)d_ws;
  unsigned short* Wt = (unsigned short*)(ws);                       // 2 MB
  unsigned*       maskb = (unsigned*)(ws + ((size_t)2 << 20));      // 1 MB
  float* f1   = (float*)(ws + ((size_t)3 << 20));                   // 512 KB
  float* f2   = (float*)(ws + ((size_t)3 << 20) + ((size_t)512 << 10));
  float* Mx   = (float*)(ws + ((size_t)4 << 20));
  float* rden = (float*)(ws + ((size_t)4 << 20) + ((size_t)512 << 10));
  _Float16* WhT = (_Float16*)(ws + ((size_t)5 << 20));              // 16 MB

  prepw_kernel<<<dim3(64, 4, 16), 256, 0, stream>>>(W, Wt);
  adjmask_kernel<<<1024, 256, 0, stream>>>(adj, maskb);
  gemm_kernel<<<dim3(64, 8), 256, 0, stream>>>(x, Wt, a1, a2, WhT, f1, f2);
  maxdenom_kernel<<<32768, 256, 0, stream>>>(f1, f2, maskb, Mx, rden);
  pv_kernel<<<dim3(8, 16, 8), 256, 0, stream>>>(WhT, f1, f2, Mx, rden, maskb, y);
}

// Round 7
// 112.033 us; speedup vs baseline: 1.8222x; 1.4299x over previous
//
#include <hip/hip_runtime.h>

typedef float    f32x4 __attribute__((ext_vector_type(4)));
typedef short    s16x8 __attribute__((ext_vector_type(8)));
typedef _Float16 f16x8 __attribute__((ext_vector_type(8)));
typedef _Float16 f16x4 __attribute__((ext_vector_type(4)));
typedef unsigned int   u32x4 __attribute__((ext_vector_type(4)));

// B=8, N=1024, F=1024, H=16, D=64
#define NEGBIG (-3.0e38f)

__device__ __forceinline__ unsigned short bf16rne(float f){
  unsigned u = __float_as_uint(f);
  return (unsigned short)((u + 0x7FFFu + ((u >> 16) & 1u)) >> 16);
}

// ---------------- prep: W[h][f][d] -> Wt[(h*64+d)][f] (bf16) ------------------
__global__ __launch_bounds__(256) void prepw_kernel(const float* __restrict__ W,
    unsigned short* __restrict__ Wt)
{
  const int tx = threadIdx.x & 15, ty = threadIdx.x >> 4;
  const int f0 = blockIdx.x * 16, d0 = blockIdx.y * 16, hh = blockIdx.z;
  __shared__ float t[16][17];
  t[ty][tx] = W[(size_t)hh * 65536 + (size_t)(f0 + ty) * 64 + (d0 + tx)];
  __syncthreads();
  float v = t[tx][ty];  // = W[hh][f0+tx][d0+ty]
  size_t o = (size_t)(hh * 64 + d0 + ty) * 1024 + (f0 + tx);
  Wt[o] = bf16rne(v);
}

// ---------------- prep: adj (int32) -> bitmask words --------------------------
__global__ __launch_bounds__(256) void adjmask_kernel(const int* __restrict__ adj,
    unsigned* __restrict__ maskb)
{
  const int lane = threadIdx.x & 63;
  int gw = (blockIdx.x * 256 + threadIdx.x) >> 6;  // wave id, 4096 total
  for (int s = gw; s < 131072; s += 4096) {
    int a = adj[(size_t)s * 64 + lane];
    unsigned long long m = __ballot(a > 0);
    if (lane == 0) {
      maskb[s * 2]     = (unsigned)m;
      maskb[s * 2 + 1] = (unsigned)(m >> 32);
    }
  }
}

// ---------------- Wh = x @ Wt^T (bf16 MFMA, fp32 accum) -----------------------
__global__ __launch_bounds__(256, 3) void gemm_kernel(const float* __restrict__ x,
    const unsigned short* __restrict__ Btg,
    const float* __restrict__ a1, const float* __restrict__ a2,
    _Float16* __restrict__ WhT, float* __restrict__ f1, float* __restrict__ f2)
{
  __shared__ unsigned short Ah[128 * 40], Bh[128 * 40];
  const int tid  = threadIdx.x;
  const int lane = tid & 63, wave = tid >> 6;
  const int m0 = blockIdx.x * 128, n0 = blockIdx.y * 128;
  const int wm = (wave & 1) * 64, wn = (wave >> 1) * 64;
  const int rA = lane & 15, kg = lane >> 4;

  f32x4 acc[4][4] = {};

  for (int k0 = 0; k0 < 1024; k0 += 32) {
#pragma unroll
    for (int r = 0; r < 4; ++r) {
      int flat = r * 256 + tid;          // float4 units, 8 per row
      int row = flat >> 3;
      int c4  = (flat & 7) << 2;
      f32x4 v = *reinterpret_cast<const f32x4*>(&x[(size_t)(m0 + row) * 1024 + k0 + c4]);
      uint2 pk;
      pk.x = (unsigned)bf16rne(v[0]) | ((unsigned)bf16rne(v[1]) << 16);
      pk.y = (unsigned)bf16rne(v[2]) | ((unsigned)bf16rne(v[3]) << 16);
      *reinterpret_cast<uint2*>(&Ah[row * 40 + c4]) = pk;
    }
#pragma unroll
    for (int r = 0; r < 2; ++r) {
      int flat = r * 256 + tid;          // 16B units, 4 per row
      int row = flat >> 2;
      int o8  = (flat & 3) << 3;
      size_t g = (size_t)(n0 + row) * 1024 + k0 + o8;
      *reinterpret_cast<u32x4*>(&Bh[row * 40 + o8]) = *reinterpret_cast<const u32x4*>(&Btg[g]);
    }
    __syncthreads();

    s16x8 ah[4], bh[4];
#pragma unroll
    for (int i = 0; i < 4; ++i)
      ah[i] = *reinterpret_cast<const s16x8*>(&Ah[(wm + i * 16 + rA) * 40 + kg * 8]);
#pragma unroll
    for (int j = 0; j < 4; ++j)
      bh[j] = *reinterpret_cast<const s16x8*>(&Bh[(wn + j * 16 + rA) * 40 + kg * 8]);
#pragma unroll
    for (int i = 0; i < 4; ++i)
#pragma unroll
      for (int j = 0; j < 4; ++j)
        acc[i][j] = __builtin_amdgcn_mfma_f32_16x16x32_bf16(ah[i], bh[j], acc[i][j], 0, 0, 0);
    __syncthreads();
  }

  // epilogue 1: WhT f16 [(bh*64+d)*1024 + n-within-batch]
#pragma unroll
  for (int i = 0; i < 4; ++i) {
    int gm0 = m0 + wm + i * 16 + kg * 4;  // 4 consecutive rows
#pragma unroll
    for (int j = 0; j < 4; ++j) {
      int gn = n0 + wn + j * 16 + rA;
      int bb = gm0 >> 10, nn = gm0 & 1023;
      int hh = gn >> 6,  dd = gn & 63;
      f16x4 hv;
#pragma unroll
      for (int jj = 0; jj < 4; ++jj) hv[jj] = (_Float16)acc[i][j][jj];
      *reinterpret_cast<f16x4*>(&WhT[((size_t)((bb * 16 + hh) * 64 + dd) << 10) + nn]) = hv;
    }
  }

  // epilogue 2: fused f1/f2 (this wave's 64 cols = one complete head)
  const int hw = (n0 + wn) >> 6;        // absolute head 0..15
  float a1v[4], a2v[4];
#pragma unroll
  for (int j = 0; j < 4; ++j) {
    int d = j * 16 + rA;
    a1v[j] = a1[hw * 64 + d];
    a2v[j] = a2[hw * 64 + d];
  }
#pragma unroll
  for (int i = 0; i < 4; ++i) {
#pragma unroll
    for (int jj = 0; jj < 4; ++jj) {
      float s1 = 0.f, s2 = 0.f;
#pragma unroll
      for (int j = 0; j < 4; ++j) {
        float v = acc[i][j][jj];
        s1 += v * a1v[j];
        s2 += v * a2v[j];
      }
#pragma unroll
      for (int off = 1; off < 16; off <<= 1) {
        s1 += __shfl_xor(s1, off);
        s2 += __shfl_xor(s2, off);
      }
      if (rA == 0) {
        int gm = m0 + wm + i * 16 + kg * 4 + jj;
        int bb = gm >> 10, nn = gm & 1023;
        size_t o = (size_t)(bb * 16 + hw) * 1024 + nn;
        f1[o] = s1;
        f2[o] = s2;
      }
    }
  }
}

// ---------------- PV: p = exp2(lrelu(f1'+f2') - M'), fused denominator -------
// All scores pre-scaled by log2e; M' = lrelu(f1' + max_j f2') >= per-row max,
// cancels exactly between numerator and denominator (both use the same p).
__global__ __launch_bounds__(256, 4) void pv_kernel(const _Float16* __restrict__ WhT,
    const float* __restrict__ f1, const float* __restrict__ f2,
    const unsigned* __restrict__ maskb, float* __restrict__ y)
{
  const int tid = threadIdx.x, lane = tid & 63, wave = tid >> 6;
  const int rb = blockIdx.x, h = blockIdx.y, b = blockIdx.z;
  const int bh = b * 16 + h;
  const int n0 = rb * 128;
  const _Float16* whtb = WhT + ((size_t)bh << 16);  // 64*1024 per (b,h)

  __shared__ _Float16 Bsh[64 * 72];
  __shared__ float f2s[1024];      // f2 * log2e
  __shared__ unsigned msk[128 * 33];
  __shared__ float smx[4];
  __shared__ float rowR[128];

  const float K = 1.44269504f;

  // phase 0: stage scaled f2 (+ block max), masks
  float pmax;
  {
    f32x4 fv = *reinterpret_cast<const f32x4*>(&f2[(size_t)bh * 1024 + tid * 4]);
    f32x4 sv;
#pragma unroll
    for (int e = 0; e < 4; ++e) sv[e] = fv[e] * K;
    *reinterpret_cast<f32x4*>(&f2s[tid * 4]) = sv;
    pmax = fmaxf(fmaxf(sv[0], sv[1]), fmaxf(sv[2], sv[3]));
  }
#pragma unroll
  for (int off = 32; off; off >>= 1) pmax = fmaxf(pmax, __shfl_xor(pmax, off));
  if (lane == 0) smx[wave] = pmax;
#pragma unroll
  for (int r = 0; r < 16; ++r) {
    int flat = r * 256 + tid;  // 0..4095
    int row = flat >> 5, w = flat & 31;
    msk[row * 33 + w] = maskb[((size_t)(b << 10) + n0 + row) * 32 + w];
  }
  __syncthreads();

  const float m2s = fmaxf(fmaxf(smx[0], smx[1]), fmaxf(smx[2], smx[3]));

  const int rA = lane & 15, kg = lane >> 4;
  const int wrow = wave * 32;
  f32x4 acc[2][4] = {};
  int   rloc[2];
  float f1p[2], Mp[2], den[2];
#pragma unroll
  for (int t = 0; t < 2; ++t) {
    rloc[t] = wrow + t * 16 + rA;
    f1p[t] = f1[(size_t)bh * 1024 + n0 + rloc[t]] * K;
    float sf = f1p[t] + m2s;
    Mp[t] = fmaxf(sf, 0.2f * sf);
    den[t] = 0.f;
  }

  for (int m0 = 0; m0 < 1024; m0 += 64) {
    // stage Bsh = WhT[d][m0..m0+64) f16, padded stride 72
#pragma unroll
    for (int r = 0; r < 2; ++r) {
      int flat = r * 256 + tid;
      int d = flat >> 3, o = (flat & 7) << 3;
      *reinterpret_cast<u32x4*>(&Bsh[d * 72 + o]) =
          *reinterpret_cast<const u32x4*>(&whtb[(size_t)d * 1024 + m0 + o]);
    }
    __syncthreads();
#pragma unroll
    for (int ks = 0; ks < 2; ++ks) {
      const int kc = m0 + ks * 32 + kg * 8;
      f32x4 fa = *reinterpret_cast<const f32x4*>(&f2s[kc]);
      f32x4 fb = *reinterpret_cast<const f32x4*>(&f2s[kc + 4]);
      f16x8 pa[2];
#pragma unroll
      for (int t = 0; t < 2; ++t) {
        unsigned mw = msk[rloc[t] * 33 + (m0 >> 5) + ks] >> (kg * 8);
#pragma unroll
        for (int jj = 0; jj < 8; ++jj) {
          float f2j = (jj < 4) ? fa[jj] : fb[jj - 4];
          float s = f1p[t] + f2j;
          float e = fmaxf(s, 0.2f * s);
          float p = ((mw >> jj) & 1u) ? __builtin_amdgcn_exp2f(e - Mp[t]) : 0.0f;
          den[t] += p;
          pa[t][jj] = (_Float16)p;
        }
      }
#pragma unroll
      for (int j = 0; j < 4; ++j) {
        f16x8 bf = *reinterpret_cast<const f16x8*>(&Bsh[(j * 16 + rA) * 72 + ks * 32 + kg * 8]);
        acc[0][j] = __builtin_amdgcn_mfma_f32_16x16x32_f16(pa[0], bf, acc[0][j], 0, 0, 0);
        acc[1][j] = __builtin_amdgcn_mfma_f32_16x16x32_f16(pa[1], bf, acc[1][j], 0, 0, 0);
      }
    }
    __syncthreads();
  }

  // reduce denominator across the 4 k-groups, publish 1/den per row
#pragma unroll
  for (int t = 0; t < 2; ++t) {
    den[t] += __shfl_xor(den[t], 16);
    den[t] += __shfl_xor(den[t], 32);
    if (kg == 0) rowR[rloc[t]] = den[t] > 0.f ? 1.0f / den[t] : 0.f;
  }
  __syncthreads();

#pragma unroll
  for (int t = 0; t < 2; ++t) {
#pragma unroll
    for (int j = 0; j < 4; ++j) {
#pragma unroll
      for (int jj = 0; jj < 4; ++jj) {
        int row = wrow + t * 16 + kg * 4 + jj;
        int n = n0 + row, d = j * 16 + rA;
        y[(((size_t)b * 1024 + n) << 10) + h * 64 + d] = acc[t][j][jj] * rowR[row];
      }
    }
  }
}

extern "C" void kernel_launch(void* const* d_in, const int* in_sizes, int n_in,
                              void* d_out, int out_size, void* d_ws, size_t ws_size,
                              hipStream_t stream)
{
  const float* x  = (const float*)d_in[0];
  const int*   adj = (const int*)d_in[1];
  const float* W  = (const float*)d_in[2];
  const float* a1 = (const float*)d_in[3];
  const float* a2 = (const float*)d_in[4];
  float* y = (float*)d_out;

  char* ws = (char*)d_ws;
  unsigned short* Wt = (unsigned short*)(ws);                       // 2 MB
  unsigned*       maskb = (unsigned*)(ws + ((size_t)2 << 20));      // 1 MB
  float* f1   = (float*)(ws + ((size_t)3 << 20));                   // 512 KB
  float* f2   = (float*)(ws + ((size_t)3 << 20) + ((size_t)512 << 10));
  _Float16* WhT = (_Float16*)(ws + ((size_t)5 << 20));              // 16 MB

  prepw_kernel<<<dim3(64, 4, 16), 256, 0, stream>>>(W, Wt);
  adjmask_kernel<<<1024, 256, 0, stream>>>(adj, maskb);
  gemm_kernel<<<dim3(64, 8), 256, 0, stream>>>(x, Wt, a1, a2, WhT, f1, f2);
  pv_kernel<<<dim3(8, 16, 8), 256, 0, stream>>>(WhT, f1, f2, maskb, y);
}

// Round 8
// 110.131 us; speedup vs baseline: 1.8537x; 1.0173x over previous
//
#include <hip/hip_runtime.h>

typedef float    f32x4 __attribute__((ext_vector_type(4)));
typedef short    s16x8 __attribute__((ext_vector_type(8)));
typedef _Float16 f16x8 __attribute__((ext_vector_type(8)));
typedef _Float16 f16x4 __attribute__((ext_vector_type(4)));
typedef unsigned int   u32x4 __attribute__((ext_vector_type(4)));

// B=8, N=1024, F=1024, H=16, D=64
#define NEGBIG (-3.0e38f)

__device__ __forceinline__ unsigned short bf16rne(float f){
  unsigned u = __float_as_uint(f);
  return (unsigned short)((u + 0x7FFFu + ((u >> 16) & 1u)) >> 16);
}

// ---------------- prep: W[h][f][d] -> Wt[(h*64+d)][f] (bf16) ------------------
__global__ __launch_bounds__(256) void prepw_kernel(const float* __restrict__ W,
    unsigned short* __restrict__ Wt)
{
  const int tx = threadIdx.x & 15, ty = threadIdx.x >> 4;
  const int f0 = blockIdx.x * 16, d0 = blockIdx.y * 16, hh = blockIdx.z;
  __shared__ float t[16][17];
  t[ty][tx] = W[(size_t)hh * 65536 + (size_t)(f0 + ty) * 64 + (d0 + tx)];
  __syncthreads();
  float v = t[tx][ty];  // = W[hh][f0+tx][d0+ty]
  size_t o = (size_t)(hh * 64 + d0 + ty) * 1024 + (f0 + tx);
  Wt[o] = bf16rne(v);
}

// ---------------- prep: adj (int32) -> bitmask words --------------------------
__global__ __launch_bounds__(256) void adjmask_kernel(const int* __restrict__ adj,
    unsigned* __restrict__ maskb)
{
  const int lane = threadIdx.x & 63;
  int gw = (blockIdx.x * 256 + threadIdx.x) >> 6;  // wave id, 4096 total
  for (int s = gw; s < 131072; s += 4096) {
    int a = adj[(size_t)s * 64 + lane];
    unsigned long long m = __ballot(a > 0);
    if (lane == 0) {
      maskb[s * 2]     = (unsigned)m;
      maskb[s * 2 + 1] = (unsigned)(m >> 32);
    }
  }
}

// ---------------- Wh = x @ Wt^T (bf16 MFMA, fp32 accum) -----------------------
__global__ __launch_bounds__(256, 3) void gemm_kernel(const float* __restrict__ x,
    const unsigned short* __restrict__ Btg,
    const float* __restrict__ a1, const float* __restrict__ a2,
    _Float16* __restrict__ WhT, float* __restrict__ f1, float* __restrict__ f2)
{
  __shared__ unsigned short Ah[128 * 40], Bh[128 * 40];
  const int tid  = threadIdx.x;
  const int lane = tid & 63, wave = tid >> 6;
  const int m0 = blockIdx.x * 128, n0 = blockIdx.y * 128;
  const int wm = (wave & 1) * 64, wn = (wave >> 1) * 64;
  const int rA = lane & 15, kg = lane >> 4;

  f32x4 acc[4][4] = {};

  for (int k0 = 0; k0 < 1024; k0 += 32) {
#pragma unroll
    for (int r = 0; r < 4; ++r) {
      int flat = r * 256 + tid;          // float4 units, 8 per row
      int row = flat >> 3;
      int c4  = (flat & 7) << 2;
      f32x4 v = *reinterpret_cast<const f32x4*>(&x[(size_t)(m0 + row) * 1024 + k0 + c4]);
      uint2 pk;
      pk.x = (unsigned)bf16rne(v[0]) | ((unsigned)bf16rne(v[1]) << 16);
      pk.y = (unsigned)bf16rne(v[2]) | ((unsigned)bf16rne(v[3]) << 16);
      *reinterpret_cast<uint2*>(&Ah[row * 40 + c4]) = pk;
    }
#pragma unroll
    for (int r = 0; r < 2; ++r) {
      int flat = r * 256 + tid;          // 16B units, 4 per row
      int row = flat >> 2;
      int o8  = (flat & 3) << 3;
      size_t g = (size_t)(n0 + row) * 1024 + k0 + o8;
      *reinterpret_cast<u32x4*>(&Bh[row * 40 + o8]) = *reinterpret_cast<const u32x4*>(&Btg[g]);
    }
    __syncthreads();

    s16x8 ah[4], bh[4];
#pragma unroll
    for (int i = 0; i < 4; ++i)
      ah[i] = *reinterpret_cast<const s16x8*>(&Ah[(wm + i * 16 + rA) * 40 + kg * 8]);
#pragma unroll
    for (int j = 0; j < 4; ++j)
      bh[j] = *reinterpret_cast<const s16x8*>(&Bh[(wn + j * 16 + rA) * 40 + kg * 8]);
#pragma unroll
    for (int i = 0; i < 4; ++i)
#pragma unroll
      for (int j = 0; j < 4; ++j)
        acc[i][j] = __builtin_amdgcn_mfma_f32_16x16x32_bf16(ah[i], bh[j], acc[i][j], 0, 0, 0);
    __syncthreads();
  }

  // epilogue 1: WhT f16 [(bh*64+d)*1024 + n-within-batch]
#pragma unroll
  for (int i = 0; i < 4; ++i) {
    int gm0 = m0 + wm + i * 16 + kg * 4;  // 4 consecutive rows
#pragma unroll
    for (int j = 0; j < 4; ++j) {
      int gn = n0 + wn + j * 16 + rA;
      int bb = gm0 >> 10, nn = gm0 & 1023;
      int hh = gn >> 6,  dd = gn & 63;
      f16x4 hv;
#pragma unroll
      for (int jj = 0; jj < 4; ++jj) hv[jj] = (_Float16)acc[i][j][jj];
      *reinterpret_cast<f16x4*>(&WhT[((size_t)((bb * 16 + hh) * 64 + dd) << 10) + nn]) = hv;
    }
  }

  // epilogue 2: fused f1/f2 (this wave's 64 cols = one complete head)
  const int hw = (n0 + wn) >> 6;        // absolute head 0..15
  float a1v[4], a2v[4];
#pragma unroll
  for (int j = 0; j < 4; ++j) {
    int d = j * 16 + rA;
    a1v[j] = a1[hw * 64 + d];
    a2v[j] = a2[hw * 64 + d];
  }
#pragma unroll
  for (int i = 0; i < 4; ++i) {
#pragma unroll
    for (int jj = 0; jj < 4; ++jj) {
      float s1 = 0.f, s2 = 0.f;
#pragma unroll
      for (int j = 0; j < 4; ++j) {
        float v = acc[i][j][jj];
        s1 += v * a1v[j];
        s2 += v * a2v[j];
      }
#pragma unroll
      for (int off = 1; off < 16; off <<= 1) {
        s1 += __shfl_xor(s1, off);
        s2 += __shfl_xor(s2, off);
      }
      if (rA == 0) {
        int gm = m0 + wm + i * 16 + kg * 4 + jj;
        int bb = gm >> 10, nn = gm & 1023;
        size_t o = (size_t)(bb * 16 + hw) * 1024 + nn;
        f1[o] = s1;
        f2[o] = s2;
      }
    }
  }
}

// ---------------- PV: factorized p, fused denominator -------------------------
// p = 2^(lrelu(f1'+f2') - M') with scores pre-scaled by log2e.
//   s' > 0 branch: p = A*C,  A = 2^(f1'-M'),   C = 2^(f2')     (per row / per col)
//   s' <= 0      : p = B*D,  B = 2^(0.2f1'-M'), D = 2^(0.2f2')
// Branch predicate f2' > -f1' is exactly the fmax predicate of the direct form.
// M' = lrelu(f1' + max_j f2') >= row max; cancels exactly (den uses same p).
__global__ __launch_bounds__(256, 4) void pv_kernel(const _Float16* __restrict__ WhT,
    const float* __restrict__ f1, const float* __restrict__ f2,
    const unsigned* __restrict__ maskb, float* __restrict__ y)
{
  const int tid = threadIdx.x, lane = tid & 63, wave = tid >> 6;
  const int rb = blockIdx.x, h = blockIdx.y, b = blockIdx.z;
  const int bh = b * 16 + h;
  const int n0 = rb * 128;
  const _Float16* whtb = WhT + ((size_t)bh << 16);  // 64*1024 per (b,h)

  __shared__ _Float16 Bsh[64 * 72];
  __shared__ float f2s[1024];      // f2 * log2e
  __shared__ float Cs[1024], Ds[1024];
  __shared__ unsigned msk[128 * 33];
  __shared__ float smx[4];
  __shared__ float rowR[128];

  const float K = 1.44269504f;

  // phase 0: stage scaled f2, C=2^f2', D=2^0.2f2' (+ block max), masks
  float pmax;
  {
    f32x4 fv = *reinterpret_cast<const f32x4*>(&f2[(size_t)bh * 1024 + tid * 4]);
    f32x4 sv, cv, dv;
#pragma unroll
    for (int e = 0; e < 4; ++e) {
      sv[e] = fv[e] * K;
      cv[e] = __builtin_amdgcn_exp2f(sv[e]);
      dv[e] = __builtin_amdgcn_exp2f(0.2f * sv[e]);
    }
    *reinterpret_cast<f32x4*>(&f2s[tid * 4]) = sv;
    *reinterpret_cast<f32x4*>(&Cs[tid * 4]) = cv;
    *reinterpret_cast<f32x4*>(&Ds[tid * 4]) = dv;
    pmax = fmaxf(fmaxf(sv[0], sv[1]), fmaxf(sv[2], sv[3]));
  }
#pragma unroll
  for (int off = 32; off; off >>= 1) pmax = fmaxf(pmax, __shfl_xor(pmax, off));
  if (lane == 0) smx[wave] = pmax;
#pragma unroll
  for (int r = 0; r < 16; ++r) {
    int flat = r * 256 + tid;  // 0..4095
    int row = flat >> 5, w = flat & 31;
    msk[row * 33 + w] = maskb[((size_t)(b << 10) + n0 + row) * 32 + w];
  }
  __syncthreads();

  const float m2s = fmaxf(fmaxf(smx[0], smx[1]), fmaxf(smx[2], smx[3]));

  const int rA = lane & 15, kg = lane >> 4;
  const int wrow = wave * 32;
  f32x4 acc[2][4] = {};
  int   rloc[2];
  float At[2], Bt[2], nf1[2], den[2];
#pragma unroll
  for (int t = 0; t < 2; ++t) {
    rloc[t] = wrow + t * 16 + rA;
    float f1p = f1[(size_t)bh * 1024 + n0 + rloc[t]] * K;
    float sf = f1p + m2s;
    float Mp = fmaxf(sf, 0.2f * sf);
    At[t]  = __builtin_amdgcn_exp2f(f1p - Mp);
    Bt[t]  = __builtin_amdgcn_exp2f(0.2f * f1p - Mp);
    nf1[t] = -f1p;
    den[t] = 0.f;
  }

  for (int m0 = 0; m0 < 1024; m0 += 64) {
    // stage Bsh = WhT[d][m0..m0+64) f16, padded stride 72
#pragma unroll
    for (int r = 0; r < 2; ++r) {
      int flat = r * 256 + tid;
      int d = flat >> 3, o = (flat & 7) << 3;
      *reinterpret_cast<u32x4*>(&Bsh[d * 72 + o]) =
          *reinterpret_cast<const u32x4*>(&whtb[(size_t)d * 1024 + m0 + o]);
    }
    __syncthreads();
#pragma unroll
    for (int ks = 0; ks < 2; ++ks) {
      const int kc = m0 + ks * 32 + kg * 8;
      f32x4 fa = *reinterpret_cast<const f32x4*>(&f2s[kc]);
      f32x4 fb = *reinterpret_cast<const f32x4*>(&f2s[kc + 4]);
      f32x4 ca = *reinterpret_cast<const f32x4*>(&Cs[kc]);
      f32x4 cb = *reinterpret_cast<const f32x4*>(&Cs[kc + 4]);
      f32x4 da = *reinterpret_cast<const f32x4*>(&Ds[kc]);
      f32x4 db = *reinterpret_cast<const f32x4*>(&Ds[kc + 4]);
      f16x8 pa[2];
#pragma unroll
      for (int t = 0; t < 2; ++t) {
        unsigned mw = msk[rloc[t] * 33 + (m0 >> 5) + ks] >> (kg * 8);
#pragma unroll
        for (int jj = 0; jj < 8; ++jj) {
          float f2j = (jj < 4) ? fa[jj] : fb[jj - 4];
          float C   = (jj < 4) ? ca[jj] : cb[jj - 4];
          float D   = (jj < 4) ? da[jj] : db[jj - 4];
          bool pos = f2j > nf1[t];
          float pr = pos ? At[t] : Bt[t];
          float pc = pos ? C : D;
          float p = ((mw >> jj) & 1u) ? pr * pc : 0.0f;
          den[t] += p;
          pa[t][jj] = (_Float16)p;
        }
      }
#pragma unroll
      for (int j = 0; j < 4; ++j) {
        f16x8 bf = *reinterpret_cast<const f16x8*>(&Bsh[(j * 16 + rA) * 72 + ks * 32 + kg * 8]);
        acc[0][j] = __builtin_amdgcn_mfma_f32_16x16x32_f16(pa[0], bf, acc[0][j], 0, 0, 0);
        acc[1][j] = __builtin_amdgcn_mfma_f32_16x16x32_f16(pa[1], bf, acc[1][j], 0, 0, 0);
      }
    }
    __syncthreads();
  }

  // reduce denominator across the 4 k-groups, publish 1/den per row
#pragma unroll
  for (int t = 0; t < 2; ++t) {
    den[t] += __shfl_xor(den[t], 16);
    den[t] += __shfl_xor(den[t], 32);
    if (kg == 0) rowR[rloc[t]] = den[t] > 0.f ? 1.0f / den[t] : 0.f;
  }
  __syncthreads();

#pragma unroll
  for (int t = 0; t < 2; ++t) {
#pragma unroll
    for (int j = 0; j < 4; ++j) {
#pragma unroll
      for (int jj = 0; jj < 4; ++jj) {
        int row = wrow + t * 16 + kg * 4 + jj;
        int n = n0 + row, d = j * 16 + rA;
        y[(((size_t)b * 1024 + n) << 10) + h * 64 + d] = acc[t][j][jj] * rowR[row];
      }
    }
  }
}

extern "C" void kernel_launch(void* const* d_in, const int* in_sizes, int n_in,
                              void* d_out, int out_size, void* d_ws, size_t ws_size,
                              hipStream_t stream)
{
  const float* x  = (const float*)d_in[0];
  const int*   adj = (const int*)d_in[1];
  const float* W  = (const float*)d_in[2];
  const float* a1 = (const float*)d_in[3];
  const float* a2 = (const float*)d_in[4];
  float* y = (float*)d_out;

  char* ws = (char*)d_ws;
  unsigned short* Wt = (unsigned short*)(ws);                       // 2 MB
  unsigned*       maskb = (unsigned*)(ws + ((size_t)2 << 20));      // 1 MB
  float* f1   = (float*)(ws + ((size_t)3 << 20));                   // 512 KB
  float* f2   = (float*)(ws + ((size_t)3 << 20) + ((size_t)512 << 10));
  _Float16* WhT = (_Float16*)(ws + ((size_t)5 << 20));              // 16 MB

  prepw_kernel<<<dim3(64, 4, 16), 256, 0, stream>>>(W, Wt);
  adjmask_kernel<<<1024, 256, 0, stream>>>(adj, maskb);
  gemm_kernel<<<dim3(64, 8), 256, 0, stream>>>(x, Wt, a1, a2, WhT, f1, f2);
  pv_kernel<<<dim3(8, 16, 8), 256, 0, stream>>>(WhT, f1, f2, maskb, y);
}